// Round 6
// baseline (571.337 us; speedup 1.0000x reference)
//
#include <hip/hip_runtime.h>

typedef __bf16 bf16x8 __attribute__((ext_vector_type(8)));
typedef float f32x4 __attribute__((ext_vector_type(4)));
typedef unsigned short u16x8 __attribute__((ext_vector_type(8)));
typedef int i32x4 __attribute__((ext_vector_type(4)));

#define M_TOT 8192
#define K_TOT 4096
#define N_TOT 4096
#define BM 256
#define BN 256
#define BK 64
#define NT (K_TOT / BK)   // 64

__device__ __forceinline__ unsigned short f2bf(float f) {
  union { float f; unsigned int u; } v; v.f = f;
  unsigned int u = v.u;
  return (unsigned short)((u + 0x7FFFu + ((u >> 16) & 1u)) >> 16);  // RNE
}

// weight[o][i] = bf16(codebook[o, indices[o,i]]); one thread = 8 contiguous elems
__global__ __launch_bounds__(256) void deq_w(const float* __restrict__ cb,
                                             const int* __restrict__ idx,
                                             unsigned short* __restrict__ Wb) {
  size_t base = ((size_t)blockIdx.x * 256 + threadIdx.x) * 8;
  const float* crow = cb + ((base >> 12) << 8);  // row = base/4096, 256 floats/row
  i32x4 i0 = *(const i32x4*)(idx + base);
  i32x4 i1 = *(const i32x4*)(idx + base + 4);
  u16x8 o;
#pragma unroll
  for (int j = 0; j < 4; ++j) { o[j] = f2bf(crow[i0[j]]); o[4 + j] = f2bf(crow[i1[j]]); }
  *(u16x8*)(Wb + base) = o;
}

// x f32 -> bf16
__global__ __launch_bounds__(256) void conv_x(const float* __restrict__ X,
                                              unsigned short* __restrict__ Xc) {
  size_t base = ((size_t)blockIdx.x * 256 + threadIdx.x) * 8;
  f32x4 a = *(const f32x4*)(X + base);
  f32x4 b = *(const f32x4*)(X + base + 4);
  u16x8 o;
#pragma unroll
  for (int j = 0; j < 4; ++j) { o[j] = f2bf(a[j]); o[4 + j] = f2bf(b[j]); }
  *(u16x8*)(Xc + base) = o;
}

#define GLDS16(g, l)                                                      \
  __builtin_amdgcn_global_load_lds(                                       \
      (__attribute__((address_space(1))) void*)(g),                       \
      (__attribute__((address_space(3))) void*)(l), 16, 0, 0)

// ============================================================================
// 256x256 tile, BK=64, 8 waves (2M x 4N). B in LDS (64KB dbuf, swizzled,
// gload_lds one tile ahead). A loaded DIRECTLY global->VGPR per k-half
// (64B-coalesced; 4-way wave dup served by L1; panel L2-resident) -- removes
// 128KB/tile of LDS reads + 32KB of writes so the LDS port (96KB/tile) and
// the A-path (L1/L2) both fit under the MFMA shadow.
// Av[8] ping-pong: kh0(t) -> kh1(t) -> kh0(t+1); compiler tracks reg deps.
// One barrier + one counted vmcnt(8) per tile. Per-wave vm FIFO per tile:
// [A-kh1 x8][B-stage x4][A-kh0(t+1) x8], order pinned by compiler barriers;
// end-of-tile vmcnt(8) leaves only the A-prefetch outstanding => staging
// retired before any wave crosses the barrier. B buffer t+1 == buffer t-1,
// whose reads completed before the t-1 end barrier => no WAR race.
// ============================================================================
__global__ __launch_bounds__(512, 2) void gemm8(const unsigned short* __restrict__ A,
                                                const unsigned short* __restrict__ B,
                                                const float* __restrict__ bias,
                                                float* __restrict__ C) {
  __shared__ __attribute__((aligned(128))) char lds[65536];

  const int tid = threadIdx.x;
  const int lane = tid & 63;
  const int wm = (tid >> 6) >> 2;   // 0..1
  const int wn = (tid >> 6) & 3;    // 0..3
  const int lr = lane & 15;
  const int kg = lane >> 4;

  const int bid = blockIdx.x;                    // nwg = 512 = 8 * 64, bijective
  const int swz = (bid & 7) * 64 + (bid >> 3);
  const int bm = swz >> 4;                       // 0..31
  const int bn = swz & 15;                       // 0..15

  // per-lane A pointer: row = bm*256 + wm*128 + lr (+ mf*16), k-offset kg*8
  const unsigned short* Arow =
      A + ((size_t)(bm * BM + wm * 128 + lr)) * K_TOT + kg * 8;
  const unsigned short* Bp = B + (size_t)bn * BN * K_TOT;

  // staging: 512 thr x 16B = 64 rows/issue, 2 issues per 128-row half
  const int srow = tid >> 3;                              // 0..63
  const int sgcol = (((tid & 7) * 16) ^ ((srow & 7) << 4)) >> 1;  // elem col (inv swizzle)
  const int wavebase = (tid & 448) << 4;                  // wave-uniform LDS base part

  // B fragment-read constants (swizzled byte cols for k-halves 0/1)
  const int cs0 = (kg << 4) ^ ((lr & 7) << 4);
  const int cs1 = (64 + (kg << 4)) ^ ((lr & 7) << 4);
  const int rowB0 = (wn * 64 + lr) * 128;           // byte base of B frags (per buffer)

#define RD(off) (*(const bf16x8*)(lds + (off)))
#define STAGE(GB, TK, RB, LOFF)                                               \
  { _Pragma("unroll")                                                         \
    for (int ii = 0; ii < 2; ++ii) {                                          \
      GLDS16((GB) + (size_t)((RB) + ii * 64 + srow) * K_TOT + (TK) + sgcol,   \
             lds + (LOFF) + ii * 8192 + wavebase);                            \
    } }
#define CBAR() asm volatile("" ::: "memory")
#define BARRIER()                       \
  {                                     \
    asm volatile("" ::: "memory");      \
    __builtin_amdgcn_s_barrier();       \
    asm volatile("" ::: "memory");      \
  }

#define MFMA_KH(KH)                                                           \
  { __builtin_amdgcn_s_setprio(1);                                            \
    _Pragma("unroll") for (int mf = 0; mf < 8; ++mf) {                        \
      _Pragma("unroll") for (int nf = 0; nf < 4; ++nf)                        \
        acc[mf][nf] = __builtin_amdgcn_mfma_f32_16x16x32_bf16(                \
            Av[mf], Bv[nf * 2 + (KH)], acc[mf][nf], 0, 0, 0);                 \
    }                                                                         \
    __builtin_amdgcn_s_setprio(0); }

#define ALOAD(KOFF)                                                           \
  { _Pragma("unroll") for (int mf = 0; mf < 8; ++mf)                          \
      Av[mf] = *(const bf16x8*)(Arow + (size_t)mf * 16 * K_TOT + (KOFF)); }

// One K-tile. BO = LDS buffer byte offset (compile-time), STG/PREF flags.
#define TILE(T, BO, STG, PREF)                                                \
  {                                                                           \
    /* B frags for tile T: 8 ds_read_b128 (compiler inserts lgkm waits) */    \
    _Pragma("unroll") for (int nf = 0; nf < 4; ++nf) {                        \
      Bv[nf * 2 + 0] = RD((BO) + rowB0 + nf * 2048 + cs0);                    \
      Bv[nf * 2 + 1] = RD((BO) + rowB0 + nf * 2048 + cs1);                    \
    }                                                                         \
    MFMA_KH(0); /* uses Av = A-kh0(T), loaded last tile */                    \
    ALOAD((T) * BK + 32); /* A-kh1(T) -> Av (after last kh0 use) */           \
    CBAR();                                                                   \
    if (STG) {                                                                \
      STAGE(Bp, ((T) + 1) * BK, 0, ((BO) ^ 32768));                           \
      STAGE(Bp, ((T) + 1) * BK, 128, ((BO) ^ 32768) + 16384);                 \
    }                                                                         \
    CBAR();                                                                   \
    MFMA_KH(1);                                                               \
    if (PREF) ALOAD(((T) + 1) * BK); /* A-kh0(T+1) -> Av */                   \
    if (STG) {                                                                \
      asm volatile("s_waitcnt vmcnt(8)" ::: "memory");                        \
      BARRIER();                                                              \
    }                                                                         \
  }

  f32x4 acc[8][4] = {};
  bf16x8 Av[8], Bv[8];

  // ---- prologue: stage B(0); issue A-kh0(0); retire staging; barrier ----
  STAGE(Bp, 0, 0, 0);
  STAGE(Bp, 0, 128, 16384);
  CBAR();
  ALOAD(0);
  asm volatile("s_waitcnt vmcnt(8)" ::: "memory");
  BARRIER();

  // main loop: tiles 0..61 in pairs, 62 normal, 63 tail (no stage/pref/barrier)
  for (int t = 0; t < NT - 2; t += 2) {
    TILE(t,     0,     1, 1);
    TILE(t + 1, 32768, 1, 1);
  }
  TILE(NT - 2, 0,     1, 1);
  TILE(NT - 1, 32768, 0, 0);

  // ---- epilogue: C = acc + bias ----
  const int lg4 = kg << 2;
#pragma unroll
  for (int nf = 0; nf < 4; ++nf) {
    const int col = bn * BN + wn * 64 + nf * 16 + lr;
    const float bv = bias[col];
#pragma unroll
    for (int mf = 0; mf < 8; ++mf) {
      const int row0 = bm * BM + wm * 128 + mf * 16 + lg4;
      float* cp = C + (size_t)row0 * N_TOT + col;
#pragma unroll
      for (int j = 0; j < 4; ++j) cp[(size_t)j * N_TOT] = acc[mf][nf][j] + bv;
    }
  }
#undef RD
#undef STAGE
#undef CBAR
#undef BARRIER
#undef MFMA_KH
#undef ALOAD
#undef TILE
}

extern "C" void kernel_launch(void* const* d_in, const int* in_sizes, int n_in,
                              void* d_out, int out_size, void* d_ws, size_t ws_size,
                              hipStream_t stream) {
  const float* x    = (const float*)d_in[0];   // [4,2048,4096] f32
  const float* cb   = (const float*)d_in[1];   // [4096,256]   f32
  const float* bias = (const float*)d_in[2];   // [4096]       f32
  const int*   idx  = (const int*)d_in[3];     // [4096,4096]  int

  float* out = (float*)d_out;                  // [4,2048,4096] f32

  unsigned short* Wb = (unsigned short*)d_ws;                                      // 32 MB
  unsigned short* Xc = (unsigned short*)((char*)d_ws + (size_t)N_TOT * K_TOT * 2); // 64 MB

  deq_w<<<(N_TOT * (size_t)K_TOT) / (8 * 256), 256, 0, stream>>>(cb, idx, Wb);
  conv_x<<<((size_t)M_TOT * K_TOT) / (8 * 256), 256, 0, stream>>>(x, Xc);
  // (8192/256) * (4096/256) = 32*16 = 512 blocks, 512 threads
  gemm8<<<512, 512, 0, stream>>>(Xc, Wb, bias, out);
}

// Round 7
// 302.140 us; speedup vs baseline: 1.8910x; 1.8910x over previous
//
#include <hip/hip_runtime.h>

typedef __bf16 bf16x8 __attribute__((ext_vector_type(8)));
typedef float f32x4 __attribute__((ext_vector_type(4)));
typedef float f32x16 __attribute__((ext_vector_type(16)));
typedef unsigned short u16x8 __attribute__((ext_vector_type(8)));
typedef int i32x4 __attribute__((ext_vector_type(4)));

#define M_TOT 8192
#define K_TOT 4096
#define N_TOT 4096
#define BM 256
#define BN 256
#define BK 64
#define NT (K_TOT / BK)   // 64

__device__ __forceinline__ unsigned short f2bf(float f) {
  union { float f; unsigned int u; } v; v.f = f;
  unsigned int u = v.u;
  return (unsigned short)((u + 0x7FFFu + ((u >> 16) & 1u)) >> 16);  // RNE
}

// weight[o][i] = bf16(codebook[o, indices[o,i]]); one thread = 8 contiguous elems
__global__ __launch_bounds__(256) void deq_w(const float* __restrict__ cb,
                                             const int* __restrict__ idx,
                                             unsigned short* __restrict__ Wb) {
  size_t base = ((size_t)blockIdx.x * 256 + threadIdx.x) * 8;
  const float* crow = cb + ((base >> 12) << 8);  // row = base/4096, 256 floats/row
  i32x4 i0 = *(const i32x4*)(idx + base);
  i32x4 i1 = *(const i32x4*)(idx + base + 4);
  u16x8 o;
#pragma unroll
  for (int j = 0; j < 4; ++j) { o[j] = f2bf(crow[i0[j]]); o[4 + j] = f2bf(crow[i1[j]]); }
  *(u16x8*)(Wb + base) = o;
}

// x f32 -> bf16
__global__ __launch_bounds__(256) void conv_x(const float* __restrict__ X,
                                              unsigned short* __restrict__ Xc) {
  size_t base = ((size_t)blockIdx.x * 256 + threadIdx.x) * 8;
  f32x4 a = *(const f32x4*)(X + base);
  f32x4 b = *(const f32x4*)(X + base + 4);
  u16x8 o;
#pragma unroll
  for (int j = 0; j < 4; ++j) { o[j] = f2bf(a[j]); o[4 + j] = f2bf(b[j]); }
  *(u16x8*)(Xc + base) = o;
}

#define GLDS16(g, l)                                                      \
  __builtin_amdgcn_global_load_lds(                                       \
      (__attribute__((address_space(1))) void*)(g),                       \
      (__attribute__((address_space(3))) void*)(l), 16, 0, 0)

// ============================================================================
// R4 skeleton (2 barriers/tile, A(t+1)/B(t+2) staging, counted vmcnt(4),
// XOR-swizzled LDS, A+B in LDS) with the MFMA shape switched to
// v_mfma_f32_32x32x16_bf16 (2495 TF ceiling vs 2075; 32 MFMA/wave/tile
// instead of 64; longer per-MFMA shadows for the scheduler).
// Wave tile 128x64 = 4 m-frags x 2 n-frags of 32x32, K-tile = 4 k-steps.
// Frag: row/col = lane&31, k = (lane>>5)*8 + j. C/D: col=lane&31,
// row=(reg&3)+8*(reg>>2)+4*(lane>>5)  [m74/m101 verified].
// Quadrant phases (m-half x k-half), 8 MFMA each; reads for the next quadrant
// issued under the current MFMA cluster (compiler-scheduled, no SGB).
// vm FIFO per tile: [A(t+1)x4 (p0,p1)][B(t+2)x4 (p2,p3)]; end vmcnt(4)
// retires B(t+1)+A(t+1) staged last tile, leaves B(t+2) in flight.
// Mid-tile lgkm0+barrier gates B(t+2) staging into current B region.
// ============================================================================
__global__ __launch_bounds__(512, 2) void gemm8(const unsigned short* __restrict__ A,
                                                const unsigned short* __restrict__ B,
                                                const float* __restrict__ bias,
                                                float* __restrict__ C) {
  __shared__ __attribute__((aligned(128))) char lds[131072];

  const int tid = threadIdx.x;
  const int lane = tid & 63;
  const int wm = (tid >> 6) >> 2;   // 0..1
  const int wn = (tid >> 6) & 3;    // 0..3
  const int l31 = lane & 31;
  const int kq = lane >> 5;         // k-half within frag (0/1)

  const int bid = blockIdx.x;                    // nwg = 512 = 8 * 64, bijective
  const int swz = (bid & 7) * 64 + (bid >> 3);
  const int bm = swz >> 4;                       // 0..31
  const int bn = swz & 15;                       // 0..15

  const unsigned short* Ap = A + (size_t)bm * BM * K_TOT;
  const unsigned short* Bp = B + (size_t)bn * BN * K_TOT;

  // staging: 512 thr x 16B = 64 rows/issue, 2 issues per 128-row half
  const int srow = tid >> 3;                              // 0..63
  const int sgcol = (((tid & 7) * 16) ^ ((srow & 7) << 4)) >> 1;  // elem col (inv swizzle)
  const int wavebase = (tid & 448) << 4;                  // wave-uniform LDS base part

  // fragment-read constants: byte col for k-step ks = (ks*32 + kq*16) ^ sxz
  const int sxz = (l31 & 7) << 4;
  const int c0 = (0 * 32 + kq * 16) ^ sxz;
  const int c1 = (1 * 32 + kq * 16) ^ sxz;
  const int c2 = (2 * 32 + kq * 16) ^ sxz;
  const int c3 = (3 * 32 + kq * 16) ^ sxz;
  const int rowA = (wm * 128 + l31) * 128;          // byte base of A frags (+mf*4096)
  const int rowB = 32768 + (wn * 64 + l31) * 128;   // byte base of B frags (+nf*4096)

#define RD(off) (*(const bf16x8*)(lds + (off)))
#define STAGE(GB, TK, RB, LOFF)                                               \
  { _Pragma("unroll")                                                         \
    for (int ii = 0; ii < 2; ++ii) {                                          \
      GLDS16((GB) + (size_t)((RB) + ii * 64 + srow) * K_TOT + (TK) + sgcol,   \
             lds + (LOFF) + ii * 8192 + wavebase);                            \
    } }
#define BARRIER()                       \
  {                                     \
    asm volatile("" ::: "memory");      \
    __builtin_amdgcn_s_barrier();       \
    asm volatile("" ::: "memory");      \
  }

// 8 MFMA for quadrant: m-frags {2*MH, 2*MH+1} x n-frags {0,1} x 2 k-steps.
// AV[mf2*2+ks2], BV[nf*2+ks2].
#define MFMA_Q(MH, AV, BV)                                                    \
  { __builtin_amdgcn_s_setprio(1);                                            \
    _Pragma("unroll") for (int mf2 = 0; mf2 < 2; ++mf2) {                     \
      _Pragma("unroll") for (int nf = 0; nf < 2; ++nf) {                      \
        _Pragma("unroll") for (int ks2 = 0; ks2 < 2; ++ks2)                   \
          acc[(MH) * 2 + mf2][nf] = __builtin_amdgcn_mfma_f32_32x32x16_bf16(  \
              AV[mf2 * 2 + ks2], BV[nf * 2 + ks2], acc[(MH) * 2 + mf2][nf],   \
              0, 0, 0);                                                       \
      }                                                                       \
    }                                                                         \
    __builtin_amdgcn_s_setprio(0); }

#define TILE(T, BO, STG_A, STG_B, VMF, DO_BAR)                                    \
  {                                                                               \
    bf16x8 Aa[4], Ab[4], Ac[4], Ad[4], Bx[4], By[4];                              \
    /* head: A mh0 kh0 (4) + B kh0 (4) */                                         \
    Aa[0] = RD((BO) + rowA + 0 * 4096 + c0);                                      \
    Aa[1] = RD((BO) + rowA + 0 * 4096 + c1);                                      \
    Aa[2] = RD((BO) + rowA + 1 * 4096 + c0);                                      \
    Aa[3] = RD((BO) + rowA + 1 * 4096 + c1);                                      \
    Bx[0] = RD((BO) + rowB + 0 * 4096 + c0);                                      \
    Bx[1] = RD((BO) + rowB + 0 * 4096 + c1);                                      \
    Bx[2] = RD((BO) + rowB + 1 * 4096 + c0);                                      \
    Bx[3] = RD((BO) + rowB + 1 * 4096 + c1);                                      \
    if (STG_A) STAGE(Ap, ((T) + 1) * BK, 0, ((BO) ^ 65536) + 0);                  \
    /* A mh1 kh0 */                                                               \
    Ab[0] = RD((BO) + rowA + 2 * 4096 + c0);                                      \
    Ab[1] = RD((BO) + rowA + 2 * 4096 + c1);                                      \
    Ab[2] = RD((BO) + rowA + 3 * 4096 + c0);                                      \
    Ab[3] = RD((BO) + rowA + 3 * 4096 + c1);                                      \
    if (STG_A) STAGE(Ap, ((T) + 1) * BK, 128, ((BO) ^ 65536) + 16384);            \
    MFMA_Q(0, Aa, Bx);                                                            \
    /* A mh0 kh1 + B kh1 (read under MFMA) */                                     \
    Ac[0] = RD((BO) + rowA + 0 * 4096 + c2);                                      \
    Ac[1] = RD((BO) + rowA + 0 * 4096 + c3);                                      \
    Ac[2] = RD((BO) + rowA + 1 * 4096 + c2);                                      \
    Ac[3] = RD((BO) + rowA + 1 * 4096 + c3);                                      \
    By[0] = RD((BO) + rowB + 0 * 4096 + c2);                                      \
    By[1] = RD((BO) + rowB + 0 * 4096 + c3);                                      \
    By[2] = RD((BO) + rowB + 1 * 4096 + c2);                                      \
    By[3] = RD((BO) + rowB + 1 * 4096 + c3);                                      \
    MFMA_Q(1, Ab, Bx);                                                            \
    asm volatile("s_waitcnt lgkmcnt(0)" ::: "memory");                            \
    BARRIER();  /* all waves' B(T) kh0+kh1 reads complete -> B region reusable */ \
    if (STG_B) STAGE(Bp, ((T) + 2) * BK, 0, (BO) + 32768);                        \
    if (STG_B) STAGE(Bp, ((T) + 2) * BK, 128, (BO) + 49152);                      \
    /* A mh1 kh1 */                                                               \
    Ad[0] = RD((BO) + rowA + 2 * 4096 + c2);                                      \
    Ad[1] = RD((BO) + rowA + 2 * 4096 + c3);                                      \
    Ad[2] = RD((BO) + rowA + 3 * 4096 + c2);                                      \
    Ad[3] = RD((BO) + rowA + 3 * 4096 + c3);                                      \
    MFMA_Q(0, Ac, By);                                                            \
    MFMA_Q(1, Ad, By);                                                            \
    asm volatile("s_waitcnt vmcnt(" VMF ")" ::: "memory");                        \
    if (DO_BAR) BARRIER();                                                        \
  }

  f32x16 acc[4][2] = {};

  // ---- prologue: stage B(0), A(0), B(1); retire B(0)+A(0); B(1) in flight ----
  STAGE(Bp, 0, 0, 32768);
  STAGE(Bp, 0, 128, 49152);
  STAGE(Ap, 0, 0, 0);
  STAGE(Ap, 0, 128, 16384);
  STAGE(Bp, BK, 0, 65536 + 32768);
  STAGE(Bp, BK, 128, 65536 + 49152);
  asm volatile("s_waitcnt vmcnt(4)" ::: "memory");
  BARRIER();

  // main loop: tiles 0..NT-3 fully pipelined; last two tiles specialized
  for (int t = 0; t < NT - 2; t += 2) {
    TILE(t,     0,     1, 1, "4", 1);
    TILE(t + 1, 65536, 1, 1, "4", 1);
  }
  TILE(NT - 2, 0,     1, 0, "0", 1);
  TILE(NT - 1, 65536, 0, 0, "0", 0);

  // ---- epilogue: C = acc + bias; C/D: col=lane&31, row=(r&3)+8*(r>>2)+4*kq ----
#pragma unroll
  for (int nf = 0; nf < 2; ++nf) {
    const int col = bn * BN + wn * 64 + nf * 32 + l31;
    const float bv = bias[col];
#pragma unroll
    for (int mf = 0; mf < 4; ++mf) {
      const int row0 = bm * BM + wm * 128 + mf * 32 + kq * 4;
#pragma unroll
      for (int r = 0; r < 16; ++r) {
        const int row = row0 + (r & 3) + 8 * (r >> 2);
        C[(size_t)row * N_TOT + col] = acc[mf][nf][r] + bv;
      }
    }
  }
#undef RD
#undef STAGE
#undef BARRIER
#undef MFMA_Q
#undef TILE
}

extern "C" void kernel_launch(void* const* d_in, const int* in_sizes, int n_in,
                              void* d_out, int out_size, void* d_ws, size_t ws_size,
                              hipStream_t stream) {
  const float* x    = (const float*)d_in[0];   // [4,2048,4096] f32
  const float* cb   = (const float*)d_in[1];   // [4096,256]   f32
  const float* bias = (const float*)d_in[2];   // [4096]       f32
  const int*   idx  = (const int*)d_in[3];     // [4096,4096]  int

  float* out = (float*)d_out;                  // [4,2048,4096] f32

  unsigned short* Wb = (unsigned short*)d_ws;                                      // 32 MB
  unsigned short* Xc = (unsigned short*)((char*)d_ws + (size_t)N_TOT * K_TOT * 2); // 64 MB

  deq_w<<<(N_TOT * (size_t)K_TOT) / (8 * 256), 256, 0, stream>>>(cb, idx, Wb);
  conv_x<<<((size_t)M_TOT * K_TOT) / (8 * 256), 256, 0, stream>>>(x, Xc);
  // (8192/256) * (4096/256) = 32*16 = 512 blocks, 512 threads
  gemm8<<<512, 512, 0, stream>>>(Xc, Wb, bias, out);
}

// Round 8
// 282.503 us; speedup vs baseline: 2.0224x; 1.0695x over previous
//
#include <hip/hip_runtime.h>

typedef __bf16 bf16x8 __attribute__((ext_vector_type(8)));
typedef float f32x4 __attribute__((ext_vector_type(4)));
typedef unsigned short u16x8 __attribute__((ext_vector_type(8)));
typedef int i32x4 __attribute__((ext_vector_type(4)));

#define M_TOT 8192
#define K_TOT 4096
#define N_TOT 4096
#define BM 256
#define BN 256
#define BK 64
#define NT (K_TOT / BK)   // 64

__device__ __forceinline__ unsigned short f2bf(float f) {
  union { float f; unsigned int u; } v; v.f = f;
  unsigned int u = v.u;
  return (unsigned short)((u + 0x7FFFu + ((u >> 16) & 1u)) >> 16);  // RNE
}

// One kernel, two jobs (saves a launch gap):
//  blocks [0, 8192):    weight[o][i] = bf16(codebook[o, indices[o,i]])
//  blocks [8192, 24576): x f32 -> bf16
__global__ __launch_bounds__(256) void prep(const float* __restrict__ cb,
                                            const int* __restrict__ idx,
                                            const float* __restrict__ X,
                                            unsigned short* __restrict__ Wb,
                                            unsigned short* __restrict__ Xc) {
  const int b = blockIdx.x;
  if (b < 8192) {
    size_t base = ((size_t)b * 256 + threadIdx.x) * 8;
    const float* crow = cb + ((base >> 12) << 8);  // row = base/4096, 256 floats/row
    i32x4 i0 = *(const i32x4*)(idx + base);
    i32x4 i1 = *(const i32x4*)(idx + base + 4);
    u16x8 o;
#pragma unroll
    for (int j = 0; j < 4; ++j) { o[j] = f2bf(crow[i0[j]]); o[4 + j] = f2bf(crow[i1[j]]); }
    *(u16x8*)(Wb + base) = o;
  } else {
    size_t base = ((size_t)(b - 8192) * 256 + threadIdx.x) * 8;
    f32x4 a = *(const f32x4*)(X + base);
    f32x4 c = *(const f32x4*)(X + base + 4);
    u16x8 o;
#pragma unroll
    for (int j = 0; j < 4; ++j) { o[j] = f2bf(a[j]); o[4 + j] = f2bf(c[j]); }
    *(u16x8*)(Xc + base) = o;
  }
}

#define GLDS16(g, l)                                                      \
  __builtin_amdgcn_global_load_lds(                                       \
      (__attribute__((address_space(1))) void*)(g),                       \
      (__attribute__((address_space(3))) void*)(l), 16, 0, 0)

// ============================================================================
// 256x256 tile, BK=64, 8 waves (2M x 4N), double-buffered 128KB LDS,
// 16x16x32 MFMA, XOR-swizzled LDS (verified conflict-free R2-R6).
// MINIMAL-SYNC tile: ONE barrier per tile, no mid-tile lgkm drain.
//  head: stage A(t+1)+B(t+1) into buffer bo^1 (8 gloads; region's last
//        reads completed before the PREVIOUS barrier -> race-free);
//        issue all 24 ds_reads (khF set then khS set).
//  body: 32 MFMA (khF) ; 32 MFMA (khS). Compiler inserts counted lgkm
//        waits per operand dep -> khS reads land under khF's MFMAs.
//  tail: vmcnt(0) -- staging aged one full tile, drain is free -- barrier.
// Every wave's LDS reads of buffer bo complete before its own last MFMA
// (compiler dep waits), hence before its barrier arrival => next tile's
// staging into bo is WAR-safe with the single barrier.
// ============================================================================
__global__ __launch_bounds__(512, 2) void gemm8(const unsigned short* __restrict__ A,
                                                const unsigned short* __restrict__ B,
                                                const float* __restrict__ bias,
                                                float* __restrict__ C) {
  __shared__ __attribute__((aligned(128))) char lds[131072];

  const int tid = threadIdx.x;
  const int lane = tid & 63;
  const int wm = (tid >> 6) >> 2;   // 0..1
  const int wn = (tid >> 6) & 3;    // 0..3
  const int lr = lane & 15;

  const int bid = blockIdx.x;                    // nwg = 512 = 8 * 64, bijective
  const int swz = (bid & 7) * 64 + (bid >> 3);
  const int bm = swz >> 4;                       // 0..31
  const int bn = swz & 15;                       // 0..15

  const unsigned short* Ap = A + (size_t)bm * BM * K_TOT;
  const unsigned short* Bp = B + (size_t)bn * BN * K_TOT;

  // staging: 512 thr x 16B = 64 rows/issue, 2 issues per 128-row half
  const int srow = tid >> 3;                              // 0..63
  const int sgcol = (((tid & 7) * 16) ^ ((srow & 7) << 4)) >> 1;  // elem col (inv swizzle)
  const int wavebase = (tid & 448) << 4;                  // wave-uniform LDS base part

  // fragment-read constants (swizzled byte cols for k-halves 0/1)
  const int cs0 = (((lane >> 4) << 4)) ^ ((lr & 7) << 4);
  const int cs1 = (64 + ((lane >> 4) << 4)) ^ ((lr & 7) << 4);
  const int rowA0 = (wm * 128 + lr) * 128;          // byte base of A frags
  const int rowB0 = 32768 + (wn * 64 + lr) * 128;   // byte base of B frags

#define RD(off) (*(const bf16x8*)(lds + (off)))
#define STAGE(GB, TK, RB, LOFF)                                               \
  { _Pragma("unroll")                                                         \
    for (int ii = 0; ii < 2; ++ii) {                                          \
      GLDS16((GB) + (size_t)((RB) + ii * 64 + srow) * K_TOT + (TK) + sgcol,   \
             lds + (LOFF) + ii * 8192 + wavebase);                            \
    } }
#define BARRIER()                       \
  {                                     \
    asm volatile("" ::: "memory");      \
    __builtin_amdgcn_s_barrier();       \
    asm volatile("" ::: "memory");      \
  }

// 32 MFMA: all 8 m-frags x 4 n-frags for one k-half's register set
#define MFMA_HALF(AV, BV)                                                     \
  { __builtin_amdgcn_s_setprio(1);                                            \
    _Pragma("unroll") for (int mf = 0; mf < 8; ++mf) {                        \
      _Pragma("unroll") for (int nf = 0; nf < 4; ++nf)                        \
        acc[mf][nf] = __builtin_amdgcn_mfma_f32_16x16x32_bf16(                \
            AV[mf], BV[nf], acc[mf][nf], 0, 0, 0);                            \
    }                                                                         \
    __builtin_amdgcn_s_setprio(0); }

#define TILE(T, BO, STG)                                                      \
  {                                                                           \
    if (STG) {                                                                \
      STAGE(Ap, ((T) + 1) * BK, 0,   ((BO) ^ 65536) + 0);                     \
      STAGE(Ap, ((T) + 1) * BK, 128, ((BO) ^ 65536) + 16384);                 \
      STAGE(Bp, ((T) + 1) * BK, 0,   ((BO) ^ 65536) + 32768);                 \
      STAGE(Bp, ((T) + 1) * BK, 128, ((BO) ^ 65536) + 49152);                 \
    }                                                                         \
    bf16x8 Af[8], As[8], Bf[4], Bs[4];                                        \
    _Pragma("unroll") for (int mf = 0; mf < 8; ++mf)                          \
        Af[mf] = RD((BO) + rowA0 + mf * 2048 + cs0);                          \
    _Pragma("unroll") for (int nf = 0; nf < 4; ++nf)                          \
        Bf[nf] = RD((BO) + rowB0 + nf * 2048 + cs0);                          \
    _Pragma("unroll") for (int mf = 0; mf < 8; ++mf)                          \
        As[mf] = RD((BO) + rowA0 + mf * 2048 + cs1);                          \
    _Pragma("unroll") for (int nf = 0; nf < 4; ++nf)                          \
        Bs[nf] = RD((BO) + rowB0 + nf * 2048 + cs1);                          \
    MFMA_HALF(Af, Bf);                                                        \
    MFMA_HALF(As, Bs);                                                        \
    if (STG) {                                                                \
      asm volatile("s_waitcnt vmcnt(0)" ::: "memory");                        \
      BARRIER();                                                              \
    }                                                                         \
  }

  f32x4 acc[8][4] = {};

  // ---- prologue: stage A(0)+B(0) into buffer 0; drain; barrier ----
  STAGE(Ap, 0, 0, 0);
  STAGE(Ap, 0, 128, 16384);
  STAGE(Bp, 0, 0, 32768);
  STAGE(Bp, 0, 128, 49152);
  asm volatile("s_waitcnt vmcnt(0)" ::: "memory");
  BARRIER();

  // main loop; last tile: no stage / no trailing sync
  for (int t = 0; t < NT - 2; t += 2) {
    TILE(t,     0,     1);
    TILE(t + 1, 65536, 1);
  }
  TILE(NT - 2, 0,     1);
  TILE(NT - 1, 65536, 0);

  // ---- epilogue: C = acc + bias ----
  const int lg4 = (lane >> 4) << 2;
#pragma unroll
  for (int nf = 0; nf < 4; ++nf) {
    const int col = bn * BN + wn * 64 + nf * 16 + lr;
    const float bv = bias[col];
#pragma unroll
    for (int mf = 0; mf < 8; ++mf) {
      const int row0 = bm * BM + wm * 128 + mf * 16 + lg4;
      float* cp = C + (size_t)row0 * N_TOT + col;
#pragma unroll
      for (int j = 0; j < 4; ++j) cp[(size_t)j * N_TOT] = acc[mf][nf][j] + bv;
    }
  }
#undef RD
#undef STAGE
#undef BARRIER
#undef MFMA_HALF
#undef TILE
}

extern "C" void kernel_launch(void* const* d_in, const int* in_sizes, int n_in,
                              void* d_out, int out_size, void* d_ws, size_t ws_size,
                              hipStream_t stream) {
  const float* x    = (const float*)d_in[0];   // [4,2048,4096] f32
  const float* cb   = (const float*)d_in[1];   // [4096,256]   f32
  const float* bias = (const float*)d_in[2];   // [4096]       f32
  const int*   idx  = (const int*)d_in[3];     // [4096,4096]  int

  float* out = (float*)d_out;                  // [4,2048,4096] f32

  unsigned short* Wb = (unsigned short*)d_ws;                                      // 32 MB
  unsigned short* Xc = (unsigned short*)((char*)d_ws + (size_t)N_TOT * K_TOT * 2); // 64 MB

  // 8192 W-blocks + 16384 X-blocks in one dispatch
  prep<<<24576, 256, 0, stream>>>(cb, idx, x, Wb, Xc);
  // (8192/256) * (4096/256) = 32*16 = 512 blocks, 512 threads
  gemm8<<<512, 512, 0, stream>>>(Xc, Wb, bias, out);
}

// Round 9
// 274.972 us; speedup vs baseline: 2.0778x; 1.0274x over previous
//
#include <hip/hip_runtime.h>

typedef __bf16 bf16x8 __attribute__((ext_vector_type(8)));
typedef float f32x4 __attribute__((ext_vector_type(4)));
typedef unsigned short u16x8 __attribute__((ext_vector_type(8)));
typedef int i32x4 __attribute__((ext_vector_type(4)));

#define M_TOT 8192
#define K_TOT 4096
#define N_TOT 4096
#define BM 256
#define BN 256
#define BK 64
#define NT (K_TOT / BK)   // 64

__device__ __forceinline__ unsigned short f2bf(float f) {
  union { float f; unsigned int u; } v; v.f = f;
  unsigned int u = v.u;
  return (unsigned short)((u + 0x7FFFu + ((u >> 16) & 1u)) >> 16);  // RNE
}

// One kernel, two jobs (saves a launch gap):
//  blocks [0, 8192):    weight[o][i] = bf16(codebook[o, indices[o,i]])
//  blocks [8192, 24576): x f32 -> bf16
__global__ __launch_bounds__(256) void prep(const float* __restrict__ cb,
                                            const int* __restrict__ idx,
                                            const float* __restrict__ X,
                                            unsigned short* __restrict__ Wb,
                                            unsigned short* __restrict__ Xc) {
  const int b = blockIdx.x;
  if (b < 8192) {
    size_t base = ((size_t)b * 256 + threadIdx.x) * 8;
    const float* crow = cb + ((base >> 12) << 8);  // row = base/4096, 256 floats/row
    i32x4 i0 = *(const i32x4*)(idx + base);
    i32x4 i1 = *(const i32x4*)(idx + base + 4);
    u16x8 o;
#pragma unroll
    for (int j = 0; j < 4; ++j) { o[j] = f2bf(crow[i0[j]]); o[4 + j] = f2bf(crow[i1[j]]); }
    *(u16x8*)(Wb + base) = o;
  } else {
    size_t base = ((size_t)(b - 8192) * 256 + threadIdx.x) * 8;
    f32x4 a = *(const f32x4*)(X + base);
    f32x4 c = *(const f32x4*)(X + base + 4);
    u16x8 o;
#pragma unroll
    for (int j = 0; j < 4; ++j) { o[j] = f2bf(a[j]); o[4 + j] = f2bf(c[j]); }
    *(u16x8*)(Xc + base) = o;
  }
}

#define GLDS16(g, l)                                                      \
  __builtin_amdgcn_global_load_lds(                                       \
      (__attribute__((address_space(1))) void*)(g),                       \
      (__attribute__((address_space(3))) void*)(l), 16, 0, 0)

// ============================================================================
// EXACT R4 structure (best measured: 227.5 us, MfmaUtil 54.5, 0 conflicts).
// 256x256 tile, BK=64, 8 waves (2M x 4N), double-buffered 128KB LDS.
// Two barriers per K-tile; ds_reads pipelined under MFMA at register level.
// Quadrant phases (m-half x k-half):
//   p0 = (mh0,kh0): Aa x Bx    p1 = (mh1,kh0): Ab x Bx
//   p2 = (mh0,kh1): Ac x By    p3 = (mh1,kh1): Ad x By
// Mid-tile lgkm0+barrier gates B(t+2) staging into the current B region.
// End-of-tile counted vmcnt(4) retires B(t+1)+A(t+1), leaves B(t+2) in
// flight. Stages per tile t: A(t+1)h0,h1 early; B(t+2)h0,h1 after mid-bar.
// ============================================================================
__global__ __launch_bounds__(512, 2) void gemm8(const unsigned short* __restrict__ A,
                                                const unsigned short* __restrict__ B,
                                                const float* __restrict__ bias,
                                                float* __restrict__ C) {
  __shared__ __attribute__((aligned(128))) char lds[131072];

  const int tid = threadIdx.x;
  const int lane = tid & 63;
  const int wm = (tid >> 6) >> 2;   // 0..1
  const int wn = (tid >> 6) & 3;    // 0..3
  const int lr = lane & 15;

  const int bid = blockIdx.x;                    // nwg = 512 = 8 * 64, bijective
  const int swz = (bid & 7) * 64 + (bid >> 3);
  const int bm = swz >> 4;                       // 0..31
  const int bn = swz & 15;                       // 0..15

  const unsigned short* Ap = A + (size_t)bm * BM * K_TOT;
  const unsigned short* Bp = B + (size_t)bn * BN * K_TOT;

  // staging: 512 thr x 16B = 64 rows/issue, 2 issues per 128-row half
  const int srow = tid >> 3;                              // 0..63
  const int sgcol = (((tid & 7) * 16) ^ ((srow & 7) << 4)) >> 1;  // elem col (inv swizzle)
  const int wavebase = (tid & 448) << 4;                  // wave-uniform LDS base part

  // fragment-read constants (swizzled byte cols for k-halves 0/1)
  const int cs0 = (((lane >> 4) << 4)) ^ ((lr & 7) << 4);
  const int cs1 = (64 + ((lane >> 4) << 4)) ^ ((lr & 7) << 4);
  const int rowA0 = (wm * 128 + lr) * 128;          // byte base of A frags
  const int rowB0 = 32768 + (wn * 64 + lr) * 128;   // byte base of B frags

#define RD(off) (*(const bf16x8*)(lds + (off)))
#define STAGE(GB, TK, RB, LOFF)                                               \
  { _Pragma("unroll")                                                         \
    for (int ii = 0; ii < 2; ++ii) {                                          \
      GLDS16((GB) + (size_t)((RB) + ii * 64 + srow) * K_TOT + (TK) + sgcol,   \
             lds + (LOFF) + ii * 8192 + wavebase);                            \
    } }
#define BARRIER()                       \
  {                                     \
    asm volatile("" ::: "memory");      \
    __builtin_amdgcn_s_barrier();       \
    asm volatile("" ::: "memory");      \
  }

// 16 MFMA for quadrant (m-half MH, one k-half): 4 A-frags x 4 B-frags
#define MFMA_Q(MH, AV, BV)                                                    \
  { __builtin_amdgcn_s_setprio(1);                                            \
    _Pragma("unroll")                                                         \
    for (int r = 0; r < 4; ++r) {                                             \
      _Pragma("unroll")                                                       \
      for (int nf = 0; nf < 4; ++nf)                                          \
        acc[(MH) * 4 + r][nf] = __builtin_amdgcn_mfma_f32_16x16x32_bf16(      \
            AV[r], BV[nf], acc[(MH) * 4 + r][nf], 0, 0, 0);                   \
    }                                                                         \
    __builtin_amdgcn_s_setprio(0); }

#define TILE(T, BO, STG_A, STG_B, VMF, DO_BAR)                                    \
  {                                                                               \
    bf16x8 Aa[4], Ab[4], Ac[4], Ad[4], Bx[4], By[4];                              \
    _Pragma("unroll") for (int r = 0; r < 4; ++r)                                 \
        Aa[r] = RD((BO) + rowA0 + r * 2048 + cs0);                                \
    _Pragma("unroll") for (int n = 0; n < 4; ++n)                                 \
        Bx[n] = RD((BO) + rowB0 + n * 2048 + cs0);                                \
    if (STG_A) STAGE(Ap, ((T) + 1) * BK, 0, ((BO) ^ 65536) + 0);                  \
    _Pragma("unroll") for (int r = 0; r < 4; ++r)                                 \
        Ab[r] = RD((BO) + rowA0 + (4 + r) * 2048 + cs0);                          \
    if (STG_A) STAGE(Ap, ((T) + 1) * BK, 128, ((BO) ^ 65536) + 16384);            \
    MFMA_Q(0, Aa, Bx);                                                            \
    _Pragma("unroll") for (int r = 0; r < 4; ++r)                                 \
        Ac[r] = RD((BO) + rowA0 + r * 2048 + cs1);                                \
    _Pragma("unroll") for (int n = 0; n < 4; ++n)                                 \
        By[n] = RD((BO) + rowB0 + n * 2048 + cs1);                                \
    MFMA_Q(1, Ab, Bx);                                                            \
    asm volatile("s_waitcnt lgkmcnt(0)" ::: "memory");                            \
    BARRIER();                                                                    \
    if (STG_B) STAGE(Bp, ((T) + 2) * BK, 0, (BO) + 32768);                        \
    if (STG_B) STAGE(Bp, ((T) + 2) * BK, 128, (BO) + 49152);                      \
    _Pragma("unroll") for (int r = 0; r < 4; ++r)                                 \
        Ad[r] = RD((BO) + rowA0 + (4 + r) * 2048 + cs1);                          \
    MFMA_Q(0, Ac, By);                                                            \
    MFMA_Q(1, Ad, By);                                                            \
    asm volatile("s_waitcnt vmcnt(" VMF ")" ::: "memory");                        \
    if (DO_BAR) BARRIER();                                                        \
  }

  f32x4 acc[8][4] = {};

  // ---- prologue: stage B(0), A(0), B(1); retire B(0)+A(0); B(1) in flight ----
  STAGE(Bp, 0, 0, 32768);
  STAGE(Bp, 0, 128, 49152);
  STAGE(Ap, 0, 0, 0);
  STAGE(Ap, 0, 128, 16384);
  STAGE(Bp, BK, 0, 65536 + 32768);
  STAGE(Bp, BK, 128, 65536 + 49152);
  asm volatile("s_waitcnt vmcnt(4)" ::: "memory");
  BARRIER();

  // main loop: tiles 0..NT-3 fully pipelined; last two tiles specialized
  for (int t = 0; t < NT - 2; t += 2) {
    TILE(t,     0,     1, 1, "4", 1);
    TILE(t + 1, 65536, 1, 1, "4", 1);
  }
  TILE(NT - 2, 0,     1, 0, "0", 1);
  TILE(NT - 1, 65536, 0, 0, "0", 0);

  // ---- epilogue: C = acc + bias ----
  const int lg4 = (lane >> 4) << 2;
#pragma unroll
  for (int nf = 0; nf < 4; ++nf) {
    const int col = bn * BN + wn * 64 + nf * 16 + lr;
    const float bv = bias[col];
#pragma unroll
    for (int mf = 0; mf < 8; ++mf) {
      const int row0 = bm * BM + wm * 128 + mf * 16 + lg4;
      float* cp = C + (size_t)row0 * N_TOT + col;
#pragma unroll
      for (int j = 0; j < 4; ++j) cp[(size_t)j * N_TOT] = acc[mf][nf][j] + bv;
    }
  }
#undef RD
#undef STAGE
#undef BARRIER
#undef MFMA_Q
#undef TILE
}

extern "C" void kernel_launch(void* const* d_in, const int* in_sizes, int n_in,
                              void* d_out, int out_size, void* d_ws, size_t ws_size,
                              hipStream_t stream) {
  const float* x    = (const float*)d_in[0];   // [4,2048,4096] f32
  const float* cb   = (const float*)d_in[1];   // [4096,256]   f32
  const float* bias = (const float*)d_in[2];   // [4096]       f32
  const int*   idx  = (const int*)d_in[3];     // [4096,4096]  int

  float* out = (float*)d_out;                  // [4,2048,4096] f32

  unsigned short* Wb = (unsigned short*)d_ws;                                      // 32 MB
  unsigned short* Xc = (unsigned short*)((char*)d_ws + (size_t)N_TOT * K_TOT * 2); // 64 MB

  // 8192 W-blocks + 16384 X-blocks in one dispatch
  prep<<<24576, 256, 0, stream>>>(cb, idx, x, Wb, Xc);
  // (8192/256) * (4096/256) = 32*16 = 512 blocks, 512 threads
  gemm8<<<512, 512, 0, stream>>>(Xc, Wb, bias, out);
}